// Round 5
// baseline (145.974 us; speedup 1.0000x reference)
//
#include <hip/hip_runtime.h>

#define BB 4
#define NN 2048
#define FF 128
#define NP 2176  // padded WhT row stride (shorts)
#define ALPHA 0.2f
#define SHIFT_C 16.0f  // exp(x-16): x=LR(f1+f2) bounded ~|10|; masked -> p=0 via bit-multiply

typedef short bf16x8 __attribute__((ext_vector_type(8)));
typedef float f32x4 __attribute__((ext_vector_type(4)));
typedef unsigned u32;

__device__ inline short f2bf(float f) {  // RNE float -> bf16 bits
    union { float f; unsigned u; } v; v.f = f;
    unsigned r = (v.u + 0x7FFFu + ((v.u >> 16) & 1u)) >> 16;
    return (short)r;
}
__device__ inline float bf2f(short s) {
    union { float f; unsigned u; } v;
    v.u = ((unsigned)(unsigned short)s) << 16;
    return v.f;
}

// ---------------------------------------------------------------------------
// k_wh: unchanged (passed).
// ---------------------------------------------------------------------------
__global__ __launch_bounds__(256) void k_wh(const float* __restrict__ h,
                                            const float* __restrict__ W,
                                            const float* __restrict__ a,
                                            const int* __restrict__ adj,
                                            short* __restrict__ WhHiT,
                                            short* __restrict__ WhLoT,
                                            float* __restrict__ f1,
                                            float* __restrict__ f2,
                                            u32* __restrict__ adjp) {
    __shared__ float Wa[2 * FF];
    __shared__ float hs[16 * 128];  // 8 KB
    int tid = threadIdx.x;
    int r0 = blockIdx.x * 16;

    {
        int fin = tid & 127;
        const float* av = (tid < 128) ? a : (a + FF);
        const float* wr = W + (size_t)fin * FF;
        float s = 0.f;
        for (int o = 0; o < FF; o += 4) {
            float4 wv = *(const float4*)(wr + o);
            float4 avv = *(const float4*)(av + o);
            s += wv.x * avv.x + wv.y * avv.y + wv.z * avv.z + wv.w * avv.w;
        }
        Wa[(tid < 128 ? 0 : FF) + fin] = s;
    }
    {
        const float4* src = (const float4*)(h + (size_t)r0 * FF);
        float4* dst = (float4*)hs;
        dst[tid] = src[tid];
        dst[256 + tid] = src[256 + tid];
    }
    // de-serialized adj pack: 512 blocks * 256 thr = 131072 = 2048 rows * 64 words
    {
        int g = blockIdx.x * 256 + tid;
        int row = g >> 6, wd = g & 63;
        const int4* ar = (const int4*)(adj + (size_t)row * NN + wd * 32);
        u32 word = 0;
#pragma unroll
        for (int q = 0; q < 8; ++q) {
            int4 v = ar[q];
            word |= (u32)(v.x > 0) << (q * 4);
            word |= (u32)(v.y > 0) << (q * 4 + 1);
            word |= (u32)(v.z > 0) << (q * 4 + 2);
            word |= (u32)(v.w > 0) << (q * 4 + 3);
        }
        adjp[row * 64 + wd] = word;
    }
    __syncthreads();

    {
        int w = tid >> 6, lane = tid & 63;
        float wa1_0 = Wa[lane], wa1_1 = Wa[lane + 64];
        float wa2_0 = Wa[FF + lane], wa2_1 = Wa[FF + lane + 64];
        for (int rr = 0; rr < 4; ++rr) {
            int rloc = w * 4 + rr;
            int row = r0 + rloc;
            float x0 = hs[rloc * FF + lane], x1 = hs[rloc * FF + lane + 64];
            float s1 = x0 * wa1_0 + x1 * wa1_1;
            float s2 = x0 * wa2_0 + x1 * wa2_1;
#pragma unroll
            for (int m = 32; m >= 1; m >>= 1) {
                s1 += __shfl_xor(s1, m, 64);
                s2 += __shfl_xor(s2, m, 64);
            }
            if (lane == 0) { f1[row] = s1; f2[row] = s2; }
        }
    }

    int f4 = (tid & 31) * 4;
    int rg = tid >> 5;  // 0..7
    float acc[2][4];
#pragma unroll
    for (int rr = 0; rr < 2; ++rr)
#pragma unroll
        for (int cc = 0; cc < 4; ++cc) acc[rr][cc] = 0.f;

    for (int k0 = 0; k0 < FF; k0 += 4) {
        float4 wv[4];
#pragma unroll
        for (int kk = 0; kk < 4; ++kk)
            wv[kk] = *(const float4*)(W + (size_t)(k0 + kk) * FF + f4);
        float4 hv[2];
#pragma unroll
        for (int rr = 0; rr < 2; ++rr)
            hv[rr] = *(const float4*)(hs + (rg * 2 + rr) * FF + k0);
#pragma unroll
        for (int rr = 0; rr < 2; ++rr) {
            float hk[4] = {hv[rr].x, hv[rr].y, hv[rr].z, hv[rr].w};
#pragma unroll
            for (int kk = 0; kk < 4; ++kk) {
                acc[rr][0] += hk[kk] * wv[kk].x;
                acc[rr][1] += hk[kk] * wv[kk].y;
                acc[rr][2] += hk[kk] * wv[kk].z;
                acc[rr][3] += hk[kk] * wv[kk].w;
            }
        }
    }
    int rloc = r0 + rg * 2;
    int b = rloc >> 11;
    int j = rloc & (NN - 1);  // even
#pragma unroll
    for (int cc = 0; cc < 4; ++cc) {
        float v0 = acc[0][cc], v1 = acc[1][cc];
        short h0 = f2bf(v0), h1 = f2bf(v1);
        short l0 = f2bf(v0 - bf2f(h0)), l1 = f2bf(v1 - bf2f(h1));
        size_t off = (size_t)(b * FF + f4 + cc) * NP + j;
        *(short2*)(WhHiT + off) = make_short2(h0, h1);
        *(short2*)(WhLoT + off) = make_short2(l0, l1);
    }
}

// ---------------------------------------------------------------------------
// k_attn v9 (resubmit; round-4 bench was an infra failure, theory untested):
// v8's wave-autonomous structure with register pressure contained. v8's
// fully-unrolled barrier-free step loop let the scheduler hoist B loads /
// scalar prefetches across all 8 steps -> >128 VGPR demand under
// __launch_bounds__(512,4) -> suspected scratch spill (the 4x gap between
// v8's 42us and its ~10us pipe arithmetic). v9:
// - #pragma unroll 1 on the step loop (no cross-step hoisting)
// - per-step sched_barrier(0) fences: scalars | B loads | EV+MFMA
//   (scalar loads retire first -> EV compute overlaps in-flight B loads)
// - no register scalar prefetch (TLP at 4 waves/SIMD covers it)
// Live set/step ~105 VGPR < 128. Epilogue identical to v8.
// ---------------------------------------------------------------------------
#define EV(f2v, f1v, wv, bi) ({ float _t = (f1v) + (f2v); float _x = fmaxf(_t, ALPHA * _t); \
    __expf(_x - SHIFT_C) * (float)(((wv) >> (bi)) & 1u); })

__global__ __launch_bounds__(512, 4) void k_attn(const short* __restrict__ WhHiT,
                                                 const short* __restrict__ WhLoT,
                                                 const u32* __restrict__ adjp,
                                                 const float* __restrict__ f1,
                                                 const float* __restrict__ f2,
                                                 float* __restrict__ out) {
    __shared__ __align__(16) char lds[66688];  // 8 x 8KB images + row_ps 1KB + row_inv 128B
    float* row_ps = (float*)(lds + 65536);     // [8][32]
    float* row_inv = (float*)(lds + 66560);    // [32]

    int tid = threadIdx.x;
    int w = tid >> 6, lane = tid & 63;
    int blk = blockIdx.x;
    int b = blk >> 7;
    int tile = (blk >> 1) & 63;
    int half = blk & 1;
    int i0 = tile * 32;

    int r_c = lane & 15, kg = lane >> 4;

    const float* f2b = f2 + b * NN;
    float f10 = f1[b * NN + i0 + r_c];        // mi=0 row
    float f11 = f1[b * NN + i0 + 16 + r_c];   // mi=1 row
    const u32* ap0 = adjp + (size_t)(i0 + r_c) * 64;
    const u32* ap1 = adjp + (size_t)(i0 + 16 + r_c) * 64;

    // B-fragment row pointers (hi); lo at constant element delta
    const ptrdiff_t dLo = (ptrdiff_t)BB * FF * NP;
    int s0 = w * 8;  // this wave's first step (contiguous 8 steps)
    const short* pB0 = WhHiT + (size_t)(b * FF + half * 64 + 0 * 16 + r_c) * NP + s0 * 32 + kg * 8;
    const short* pB1 = WhHiT + (size_t)(b * FF + half * 64 + 1 * 16 + r_c) * NP + s0 * 32 + kg * 8;
    const short* pB2 = WhHiT + (size_t)(b * FF + half * 64 + 2 * 16 + r_c) * NP + s0 * 32 + kg * 8;
    const short* pB3 = WhHiT + (size_t)(b * FF + half * 64 + 3 * 16 + r_c) * NP + s0 * 32 + kg * 8;

    f32x4 acc0_0 = {0,0,0,0}, acc0_1 = {0,0,0,0};
    f32x4 acc1_0 = {0,0,0,0}, acc1_1 = {0,0,0,0};
    f32x4 acc2_0 = {0,0,0,0}, acc2_1 = {0,0,0,0};
    f32x4 acc3_0 = {0,0,0,0}, acc3_1 = {0,0,0,0};
    float sp0 = 0.f, sp1 = 0.f;

#pragma unroll 1
    for (int s8 = 0; s8 < 8; ++s8) {
        int s = s0 + s8;
        // scalar loads first (EV needs them; retire before B in vmcnt order)
        float4 q0 = *(const float4*)(f2b + s * 32 + kg * 8);
        float4 q1 = *(const float4*)(f2b + s * 32 + kg * 8 + 4);
        u32 w0 = ap0[s], w1 = ap1[s];
        __builtin_amdgcn_sched_barrier(0);
        // B loads for this step (8 x 16B; in flight during EV compute)
        bf16x8 bh0 = *(const bf16x8*)(pB0); bf16x8 bl0 = *(const bf16x8*)(pB0 + dLo);
        bf16x8 bh1 = *(const bf16x8*)(pB1); bf16x8 bl1 = *(const bf16x8*)(pB1 + dLo);
        bf16x8 bh2 = *(const bf16x8*)(pB2); bf16x8 bl2 = *(const bf16x8*)(pB2 + dLo);
        bf16x8 bh3 = *(const bf16x8*)(pB3); bf16x8 bl3 = *(const bf16x8*)(pB3 + dLo);
        __builtin_amdgcn_sched_barrier(0);

        // in-register A fragments: lane holds rows r_c (mi=0), 16+r_c (mi=1),
        // k-elements j = s*32 + kg*8 + e  (bit kg*8+e of adjp word s)
        union { u32 u[4]; bf16x8 v; } A0, A1;
        int bb = kg * 8;
        {
            float pa, pb;
            pa = EV(q0.x, f10, w0, bb + 0); pb = EV(q0.y, f10, w0, bb + 1);
            sp0 += pa + pb;
            asm("v_cvt_pk_bf16_f32 %0, %1, %2" : "=v"(A0.u[0]) : "v"(pa), "v"(pb));
            pa = EV(q0.z, f10, w0, bb + 2); pb = EV(q0.w, f10, w0, bb + 3);
            sp0 += pa + pb;
            asm("v_cvt_pk_bf16_f32 %0, %1, %2" : "=v"(A0.u[1]) : "v"(pa), "v"(pb));
            pa = EV(q1.x, f10, w0, bb + 4); pb = EV(q1.y, f10, w0, bb + 5);
            sp0 += pa + pb;
            asm("v_cvt_pk_bf16_f32 %0, %1, %2" : "=v"(A0.u[2]) : "v"(pa), "v"(pb));
            pa = EV(q1.z, f10, w0, bb + 6); pb = EV(q1.w, f10, w0, bb + 7);
            sp0 += pa + pb;
            asm("v_cvt_pk_bf16_f32 %0, %1, %2" : "=v"(A0.u[3]) : "v"(pa), "v"(pb));

            pa = EV(q0.x, f11, w1, bb + 0); pb = EV(q0.y, f11, w1, bb + 1);
            sp1 += pa + pb;
            asm("v_cvt_pk_bf16_f32 %0, %1, %2" : "=v"(A1.u[0]) : "v"(pa), "v"(pb));
            pa = EV(q0.z, f11, w1, bb + 2); pb = EV(q0.w, f11, w1, bb + 3);
            sp1 += pa + pb;
            asm("v_cvt_pk_bf16_f32 %0, %1, %2" : "=v"(A1.u[1]) : "v"(pa), "v"(pb));
            pa = EV(q1.x, f11, w1, bb + 4); pb = EV(q1.y, f11, w1, bb + 5);
            sp1 += pa + pb;
            asm("v_cvt_pk_bf16_f32 %0, %1, %2" : "=v"(A1.u[2]) : "v"(pa), "v"(pb));
            pa = EV(q1.z, f11, w1, bb + 6); pb = EV(q1.w, f11, w1, bb + 7);
            sp1 += pa + pb;
            asm("v_cvt_pk_bf16_f32 %0, %1, %2" : "=v"(A1.u[3]) : "v"(pa), "v"(pb));
        }

        // 8 MFMA-pairs: out = A x (Bhi + Blo), both halves into the same acc
        acc0_0 = __builtin_amdgcn_mfma_f32_16x16x32_bf16(A0.v, bh0, acc0_0, 0, 0, 0);
        acc0_0 = __builtin_amdgcn_mfma_f32_16x16x32_bf16(A0.v, bl0, acc0_0, 0, 0, 0);
        acc0_1 = __builtin_amdgcn_mfma_f32_16x16x32_bf16(A1.v, bh0, acc0_1, 0, 0, 0);
        acc0_1 = __builtin_amdgcn_mfma_f32_16x16x32_bf16(A1.v, bl0, acc0_1, 0, 0, 0);
        acc1_0 = __builtin_amdgcn_mfma_f32_16x16x32_bf16(A0.v, bh1, acc1_0, 0, 0, 0);
        acc1_0 = __builtin_amdgcn_mfma_f32_16x16x32_bf16(A0.v, bl1, acc1_0, 0, 0, 0);
        acc1_1 = __builtin_amdgcn_mfma_f32_16x16x32_bf16(A1.v, bh1, acc1_1, 0, 0, 0);
        acc1_1 = __builtin_amdgcn_mfma_f32_16x16x32_bf16(A1.v, bl1, acc1_1, 0, 0, 0);
        acc2_0 = __builtin_amdgcn_mfma_f32_16x16x32_bf16(A0.v, bh2, acc2_0, 0, 0, 0);
        acc2_0 = __builtin_amdgcn_mfma_f32_16x16x32_bf16(A0.v, bl2, acc2_0, 0, 0, 0);
        acc2_1 = __builtin_amdgcn_mfma_f32_16x16x32_bf16(A1.v, bh2, acc2_1, 0, 0, 0);
        acc2_1 = __builtin_amdgcn_mfma_f32_16x16x32_bf16(A1.v, bl2, acc2_1, 0, 0, 0);
        acc3_0 = __builtin_amdgcn_mfma_f32_16x16x32_bf16(A0.v, bh3, acc3_0, 0, 0, 0);
        acc3_0 = __builtin_amdgcn_mfma_f32_16x16x32_bf16(A0.v, bl3, acc3_0, 0, 0, 0);
        acc3_1 = __builtin_amdgcn_mfma_f32_16x16x32_bf16(A1.v, bh3, acc3_1, 0, 0, 0);
        acc3_1 = __builtin_amdgcn_mfma_f32_16x16x32_bf16(A1.v, bl3, acc3_1, 0, 0, 0);

        pB0 += 32; pB1 += 32; pB2 += 32; pB3 += 32;
        __builtin_amdgcn_sched_barrier(0);
    }

    // ---- epilogue (identical to v8, passed) ----
    sp0 += __shfl_xor(sp0, 16, 64); sp0 += __shfl_xor(sp0, 32, 64);
    sp1 += __shfl_xor(sp1, 16, 64); sp1 += __shfl_xor(sp1, 32, 64);
    if (lane < 16) {
        row_ps[w * 32 + lane] = sp0;
        row_ps[w * 32 + 16 + lane] = sp1;
    }
    // write this wave's partial image, col-major [col][row] f32, XOR-swizzled
    {
        char* img = lds + w * 8192;
#define STACC(NI, MI, A) { int ch = (((NI)*16 + r_c) * 8 + (MI)*4 + kg) ^ (r_c & 7); \
                           *(f32x4*)(img + ch * 16) = (A); }
        STACC(0, 0, acc0_0) STACC(0, 1, acc0_1)
        STACC(1, 0, acc1_0) STACC(1, 1, acc1_1)
        STACC(2, 0, acc2_0) STACC(2, 1, acc2_1)
        STACC(3, 0, acc3_0) STACC(3, 1, acc3_1)
#undef STACC
    }
    __syncthreads();
    if (tid < 32) {
        float t = 0.f;
#pragma unroll
        for (int ww = 0; ww < 8; ++ww) t += row_ps[ww * 32 + tid];
        row_inv[tid] = 1.0f / t;
    }
    __syncthreads();

    // merge 8 images + normalize + store. wave w: cols w*8+(lane>>3), rows (lane&7)*4..+3
    {
        int colg = w * 8 + (lane >> 3);
        int rq = lane & 7;
        int ch = (colg * 8 + rq) ^ (colg & 7);
        f32x4 v = {0, 0, 0, 0};
#pragma unroll
        for (int im = 0; im < 8; ++im)
            v += *(const f32x4*)(lds + im * 8192 + ch * 16);
        f32x4 rinv = *(const f32x4*)((char*)row_inv + rq * 16);
        float* ob = out + ((size_t)b * NN + i0 + rq * 4) * FF + half * 64 + colg;
#pragma unroll
        for (int q = 0; q < 4; ++q)
            ob[(size_t)q * FF] = v[q] * rinv[q];
    }
}

// ---------------------------------------------------------------------------
extern "C" void kernel_launch(void* const* d_in, const int* in_sizes, int n_in,
                              void* d_out, int out_size, void* d_ws, size_t ws_size,
                              hipStream_t stream) {
    const float* h   = (const float*)d_in[0];
    const int*   adj = (const int*)d_in[1];
    const float* W   = (const float*)d_in[2];
    const float* a   = (const float*)d_in[3];
    float* out = (float*)d_out;

    short* WhHiT = (short*)d_ws;                          // 2.13 MB
    short* WhLoT = WhHiT + (size_t)BB * FF * NP;          // 2.13 MB
    float* f1 = (float*)(WhLoT + (size_t)BB * FF * NP);   // 32 KB
    float* f2 = f1 + (size_t)BB * NN;                     // 32 KB
    u32* adjp = (u32*)(f2 + (size_t)BB * NN);             // 512 KB (total ~4.83 MB, proven)

    k_wh<<<(BB * NN) / 16, 256, 0, stream>>>(h, W, a, adj, WhHiT, WhLoT, f1, f2, adjp);
    k_attn<<<512, 512, 0, stream>>>(WhHiT, WhLoT, adjp, f1, f2, out);
}

// Round 6
// 133.230 us; speedup vs baseline: 1.0957x; 1.0957x over previous
//
#include <hip/hip_runtime.h>

#define BB 4
#define NN 2048
#define FF 128
#define NP 2176  // padded WhT row stride (shorts)
#define ALPHA 0.2f
#define SHIFT_C 16.0f  // exp(x-16): x=LR(f1+f2) bounded ~|10|; masked -> p=0 via bit-multiply

typedef short bf16x8 __attribute__((ext_vector_type(8)));
typedef float f32x4 __attribute__((ext_vector_type(4)));
typedef unsigned u32;

__device__ inline short f2bf(float f) {  // RNE float -> bf16 bits
    union { float f; unsigned u; } v; v.f = f;
    unsigned r = (v.u + 0x7FFFu + ((v.u >> 16) & 1u)) >> 16;
    return (short)r;
}
__device__ inline float bf2f(short s) {
    union { float f; unsigned u; } v;
    v.u = ((unsigned)(unsigned short)s) << 16;
    return v.f;
}

// ---------------------------------------------------------------------------
// k_wh: unchanged (passed).
// ---------------------------------------------------------------------------
__global__ __launch_bounds__(256) void k_wh(const float* __restrict__ h,
                                            const float* __restrict__ W,
                                            const float* __restrict__ a,
                                            const int* __restrict__ adj,
                                            short* __restrict__ WhHiT,
                                            short* __restrict__ WhLoT,
                                            float* __restrict__ f1,
                                            float* __restrict__ f2,
                                            u32* __restrict__ adjp) {
    __shared__ float Wa[2 * FF];
    __shared__ float hs[16 * 128];  // 8 KB
    int tid = threadIdx.x;
    int r0 = blockIdx.x * 16;

    {
        int fin = tid & 127;
        const float* av = (tid < 128) ? a : (a + FF);
        const float* wr = W + (size_t)fin * FF;
        float s = 0.f;
        for (int o = 0; o < FF; o += 4) {
            float4 wv = *(const float4*)(wr + o);
            float4 avv = *(const float4*)(av + o);
            s += wv.x * avv.x + wv.y * avv.y + wv.z * avv.z + wv.w * avv.w;
        }
        Wa[(tid < 128 ? 0 : FF) + fin] = s;
    }
    {
        const float4* src = (const float4*)(h + (size_t)r0 * FF);
        float4* dst = (float4*)hs;
        dst[tid] = src[tid];
        dst[256 + tid] = src[256 + tid];
    }
    // de-serialized adj pack: 512 blocks * 256 thr = 131072 = 2048 rows * 64 words
    {
        int g = blockIdx.x * 256 + tid;
        int row = g >> 6, wd = g & 63;
        const int4* ar = (const int4*)(adj + (size_t)row * NN + wd * 32);
        u32 word = 0;
#pragma unroll
        for (int q = 0; q < 8; ++q) {
            int4 v = ar[q];
            word |= (u32)(v.x > 0) << (q * 4);
            word |= (u32)(v.y > 0) << (q * 4 + 1);
            word |= (u32)(v.z > 0) << (q * 4 + 2);
            word |= (u32)(v.w > 0) << (q * 4 + 3);
        }
        adjp[row * 64 + wd] = word;
    }
    __syncthreads();

    {
        int w = tid >> 6, lane = tid & 63;
        float wa1_0 = Wa[lane], wa1_1 = Wa[lane + 64];
        float wa2_0 = Wa[FF + lane], wa2_1 = Wa[FF + lane + 64];
        for (int rr = 0; rr < 4; ++rr) {
            int rloc = w * 4 + rr;
            int row = r0 + rloc;
            float x0 = hs[rloc * FF + lane], x1 = hs[rloc * FF + lane + 64];
            float s1 = x0 * wa1_0 + x1 * wa1_1;
            float s2 = x0 * wa2_0 + x1 * wa2_1;
#pragma unroll
            for (int m = 32; m >= 1; m >>= 1) {
                s1 += __shfl_xor(s1, m, 64);
                s2 += __shfl_xor(s2, m, 64);
            }
            if (lane == 0) { f1[row] = s1; f2[row] = s2; }
        }
    }

    int f4 = (tid & 31) * 4;
    int rg = tid >> 5;  // 0..7
    float acc[2][4];
#pragma unroll
    for (int rr = 0; rr < 2; ++rr)
#pragma unroll
        for (int cc = 0; cc < 4; ++cc) acc[rr][cc] = 0.f;

    for (int k0 = 0; k0 < FF; k0 += 4) {
        float4 wv[4];
#pragma unroll
        for (int kk = 0; kk < 4; ++kk)
            wv[kk] = *(const float4*)(W + (size_t)(k0 + kk) * FF + f4);
        float4 hv[2];
#pragma unroll
        for (int rr = 0; rr < 2; ++rr)
            hv[rr] = *(const float4*)(hs + (rg * 2 + rr) * FF + k0);
#pragma unroll
        for (int rr = 0; rr < 2; ++rr) {
            float hk[4] = {hv[rr].x, hv[rr].y, hv[rr].z, hv[rr].w};
#pragma unroll
            for (int kk = 0; kk < 4; ++kk) {
                acc[rr][0] += hk[kk] * wv[kk].x;
                acc[rr][1] += hk[kk] * wv[kk].y;
                acc[rr][2] += hk[kk] * wv[kk].z;
                acc[rr][3] += hk[kk] * wv[kk].w;
            }
        }
    }
    int rloc = r0 + rg * 2;
    int b = rloc >> 11;
    int j = rloc & (NN - 1);  // even
#pragma unroll
    for (int cc = 0; cc < 4; ++cc) {
        float v0 = acc[0][cc], v1 = acc[1][cc];
        short h0 = f2bf(v0), h1 = f2bf(v1);
        short l0 = f2bf(v0 - bf2f(h0)), l1 = f2bf(v1 - bf2f(h1));
        size_t off = (size_t)(b * FF + f4 + cc) * NP + j;
        *(short2*)(WhHiT + off) = make_short2(h0, h1);
        *(short2*)(WhLoT + off) = make_short2(l0, l1);
    }
}

// ---------------------------------------------------------------------------
// k_attn v10: v8's wave-autonomous structure with the register allocation
// PINNED. v9's counters exposed the real failure: hipcc's default
// waves-per-eu range [4,8] made it target 8 waves/SIMD -> 64 VGPRs ->
// ~14 MB/dispatch scratch spill (WRITE_SIZE 18.4MB vs 4.1MB output).
// v10: __attribute__((amdgpu_waves_per_eu(4,4))) pins the budget at 128
// VGPR/wave (same 2 blocks/CU occupancy as v5-v9), keeps #pragma unroll 1
// (bounds cross-step hoisting to pipeliner depth that fits the budget),
// and REMOVES v9's per-step sched_barrier fences (they serialized
// load->compute; let EV overlap in-flight B loads and pipeline 1 step
// ahead). Live set ~95 VGPR + ~30 headroom for pipelining < 128.
// Epilogue identical to v8/v9 (passed twice).
// ---------------------------------------------------------------------------
#define EV(f2v, f1v, wv, bi) ({ float _t = (f1v) + (f2v); float _x = fmaxf(_t, ALPHA * _t); \
    __expf(_x - SHIFT_C) * (float)(((wv) >> (bi)) & 1u); })

__global__ __launch_bounds__(512) __attribute__((amdgpu_waves_per_eu(4, 4)))
void k_attn(const short* __restrict__ WhHiT,
            const short* __restrict__ WhLoT,
            const u32* __restrict__ adjp,
            const float* __restrict__ f1,
            const float* __restrict__ f2,
            float* __restrict__ out) {
    __shared__ __align__(16) char lds[66688];  // 8 x 8KB images + row_ps 1KB + row_inv 128B
    float* row_ps = (float*)(lds + 65536);     // [8][32]
    float* row_inv = (float*)(lds + 66560);    // [32]

    int tid = threadIdx.x;
    int w = tid >> 6, lane = tid & 63;
    int blk = blockIdx.x;
    int b = blk >> 7;
    int tile = (blk >> 1) & 63;
    int half = blk & 1;
    int i0 = tile * 32;

    int r_c = lane & 15, kg = lane >> 4;

    const float* f2b = f2 + b * NN;
    float f10 = f1[b * NN + i0 + r_c];        // mi=0 row
    float f11 = f1[b * NN + i0 + 16 + r_c];   // mi=1 row
    const u32* ap0 = adjp + (size_t)(i0 + r_c) * 64;
    const u32* ap1 = adjp + (size_t)(i0 + 16 + r_c) * 64;

    // B-fragment row pointers (hi); lo at constant element delta
    const ptrdiff_t dLo = (ptrdiff_t)BB * FF * NP;
    int s0 = w * 8;  // this wave's first step (contiguous 8 steps)
    const short* pB0 = WhHiT + (size_t)(b * FF + half * 64 + 0 * 16 + r_c) * NP + s0 * 32 + kg * 8;
    const short* pB1 = WhHiT + (size_t)(b * FF + half * 64 + 1 * 16 + r_c) * NP + s0 * 32 + kg * 8;
    const short* pB2 = WhHiT + (size_t)(b * FF + half * 64 + 2 * 16 + r_c) * NP + s0 * 32 + kg * 8;
    const short* pB3 = WhHiT + (size_t)(b * FF + half * 64 + 3 * 16 + r_c) * NP + s0 * 32 + kg * 8;

    f32x4 acc0_0 = {0,0,0,0}, acc0_1 = {0,0,0,0};
    f32x4 acc1_0 = {0,0,0,0}, acc1_1 = {0,0,0,0};
    f32x4 acc2_0 = {0,0,0,0}, acc2_1 = {0,0,0,0};
    f32x4 acc3_0 = {0,0,0,0}, acc3_1 = {0,0,0,0};
    float sp0 = 0.f, sp1 = 0.f;

#pragma unroll 1
    for (int s8 = 0; s8 < 8; ++s8) {
        int s = s0 + s8;
        // scalars for EV
        float4 q0 = *(const float4*)(f2b + s * 32 + kg * 8);
        float4 q1 = *(const float4*)(f2b + s * 32 + kg * 8 + 4);
        u32 w0 = ap0[s], w1 = ap1[s];
        // B loads for this step (8 x 16B; in flight during EV compute)
        bf16x8 bh0 = *(const bf16x8*)(pB0); bf16x8 bl0 = *(const bf16x8*)(pB0 + dLo);
        bf16x8 bh1 = *(const bf16x8*)(pB1); bf16x8 bl1 = *(const bf16x8*)(pB1 + dLo);
        bf16x8 bh2 = *(const bf16x8*)(pB2); bf16x8 bl2 = *(const bf16x8*)(pB2 + dLo);
        bf16x8 bh3 = *(const bf16x8*)(pB3); bf16x8 bl3 = *(const bf16x8*)(pB3 + dLo);

        // in-register A fragments: lane holds rows r_c (mi=0), 16+r_c (mi=1),
        // k-elements j = s*32 + kg*8 + e  (bit kg*8+e of adjp word s)
        union { u32 u[4]; bf16x8 v; } A0, A1;
        int bb = kg * 8;
        {
            float pa, pb;
            pa = EV(q0.x, f10, w0, bb + 0); pb = EV(q0.y, f10, w0, bb + 1);
            sp0 += pa + pb;
            asm("v_cvt_pk_bf16_f32 %0, %1, %2" : "=v"(A0.u[0]) : "v"(pa), "v"(pb));
            pa = EV(q0.z, f10, w0, bb + 2); pb = EV(q0.w, f10, w0, bb + 3);
            sp0 += pa + pb;
            asm("v_cvt_pk_bf16_f32 %0, %1, %2" : "=v"(A0.u[1]) : "v"(pa), "v"(pb));
            pa = EV(q1.x, f10, w0, bb + 4); pb = EV(q1.y, f10, w0, bb + 5);
            sp0 += pa + pb;
            asm("v_cvt_pk_bf16_f32 %0, %1, %2" : "=v"(A0.u[2]) : "v"(pa), "v"(pb));
            pa = EV(q1.z, f10, w0, bb + 6); pb = EV(q1.w, f10, w0, bb + 7);
            sp0 += pa + pb;
            asm("v_cvt_pk_bf16_f32 %0, %1, %2" : "=v"(A0.u[3]) : "v"(pa), "v"(pb));

            pa = EV(q0.x, f11, w1, bb + 0); pb = EV(q0.y, f11, w1, bb + 1);
            sp1 += pa + pb;
            asm("v_cvt_pk_bf16_f32 %0, %1, %2" : "=v"(A1.u[0]) : "v"(pa), "v"(pb));
            pa = EV(q0.z, f11, w1, bb + 2); pb = EV(q0.w, f11, w1, bb + 3);
            sp1 += pa + pb;
            asm("v_cvt_pk_bf16_f32 %0, %1, %2" : "=v"(A1.u[1]) : "v"(pa), "v"(pb));
            pa = EV(q1.x, f11, w1, bb + 4); pb = EV(q1.y, f11, w1, bb + 5);
            sp1 += pa + pb;
            asm("v_cvt_pk_bf16_f32 %0, %1, %2" : "=v"(A1.u[2]) : "v"(pa), "v"(pb));
            pa = EV(q1.z, f11, w1, bb + 6); pb = EV(q1.w, f11, w1, bb + 7);
            sp1 += pa + pb;
            asm("v_cvt_pk_bf16_f32 %0, %1, %2" : "=v"(A1.u[3]) : "v"(pa), "v"(pb));
        }

        // 8 MFMA-pairs: out = A x (Bhi + Blo), both halves into the same acc
        acc0_0 = __builtin_amdgcn_mfma_f32_16x16x32_bf16(A0.v, bh0, acc0_0, 0, 0, 0);
        acc0_0 = __builtin_amdgcn_mfma_f32_16x16x32_bf16(A0.v, bl0, acc0_0, 0, 0, 0);
        acc0_1 = __builtin_amdgcn_mfma_f32_16x16x32_bf16(A1.v, bh0, acc0_1, 0, 0, 0);
        acc0_1 = __builtin_amdgcn_mfma_f32_16x16x32_bf16(A1.v, bl0, acc0_1, 0, 0, 0);
        acc1_0 = __builtin_amdgcn_mfma_f32_16x16x32_bf16(A0.v, bh1, acc1_0, 0, 0, 0);
        acc1_0 = __builtin_amdgcn_mfma_f32_16x16x32_bf16(A0.v, bl1, acc1_0, 0, 0, 0);
        acc1_1 = __builtin_amdgcn_mfma_f32_16x16x32_bf16(A1.v, bh1, acc1_1, 0, 0, 0);
        acc1_1 = __builtin_amdgcn_mfma_f32_16x16x32_bf16(A1.v, bl1, acc1_1, 0, 0, 0);
        acc2_0 = __builtin_amdgcn_mfma_f32_16x16x32_bf16(A0.v, bh2, acc2_0, 0, 0, 0);
        acc2_0 = __builtin_amdgcn_mfma_f32_16x16x32_bf16(A0.v, bl2, acc2_0, 0, 0, 0);
        acc2_1 = __builtin_amdgcn_mfma_f32_16x16x32_bf16(A1.v, bh2, acc2_1, 0, 0, 0);
        acc2_1 = __builtin_amdgcn_mfma_f32_16x16x32_bf16(A1.v, bl2, acc2_1, 0, 0, 0);
        acc3_0 = __builtin_amdgcn_mfma_f32_16x16x32_bf16(A0.v, bh3, acc3_0, 0, 0, 0);
        acc3_0 = __builtin_amdgcn_mfma_f32_16x16x32_bf16(A0.v, bl3, acc3_0, 0, 0, 0);
        acc3_1 = __builtin_amdgcn_mfma_f32_16x16x32_bf16(A1.v, bh3, acc3_1, 0, 0, 0);
        acc3_1 = __builtin_amdgcn_mfma_f32_16x16x32_bf16(A1.v, bl3, acc3_1, 0, 0, 0);

        pB0 += 32; pB1 += 32; pB2 += 32; pB3 += 32;
    }

    // ---- epilogue (identical to v8/v9, passed) ----
    sp0 += __shfl_xor(sp0, 16, 64); sp0 += __shfl_xor(sp0, 32, 64);
    sp1 += __shfl_xor(sp1, 16, 64); sp1 += __shfl_xor(sp1, 32, 64);
    if (lane < 16) {
        row_ps[w * 32 + lane] = sp0;
        row_ps[w * 32 + 16 + lane] = sp1;
    }
    // write this wave's partial image, col-major [col][row] f32, XOR-swizzled
    {
        char* img = lds + w * 8192;
#define STACC(NI, MI, A) { int ch = (((NI)*16 + r_c) * 8 + (MI)*4 + kg) ^ (r_c & 7); \
                           *(f32x4*)(img + ch * 16) = (A); }
        STACC(0, 0, acc0_0) STACC(0, 1, acc0_1)
        STACC(1, 0, acc1_0) STACC(1, 1, acc1_1)
        STACC(2, 0, acc2_0) STACC(2, 1, acc2_1)
        STACC(3, 0, acc3_0) STACC(3, 1, acc3_1)
#undef STACC
    }
    __syncthreads();
    if (tid < 32) {
        float t = 0.f;
#pragma unroll
        for (int ww = 0; ww < 8; ++ww) t += row_ps[ww * 32 + tid];
        row_inv[tid] = 1.0f / t;
    }
    __syncthreads();

    // merge 8 images + normalize + store. wave w: cols w*8+(lane>>3), rows (lane&7)*4..+3
    {
        int colg = w * 8 + (lane >> 3);
        int rq = lane & 7;
        int ch = (colg * 8 + rq) ^ (colg & 7);
        f32x4 v = {0, 0, 0, 0};
#pragma unroll
        for (int im = 0; im < 8; ++im)
            v += *(const f32x4*)(lds + im * 8192 + ch * 16);
        f32x4 rinv = *(const f32x4*)((char*)row_inv + rq * 16);
        float* ob = out + ((size_t)b * NN + i0 + rq * 4) * FF + half * 64 + colg;
#pragma unroll
        for (int q = 0; q < 4; ++q)
            ob[(size_t)q * FF] = v[q] * rinv[q];
    }
}

// ---------------------------------------------------------------------------
extern "C" void kernel_launch(void* const* d_in, const int* in_sizes, int n_in,
                              void* d_out, int out_size, void* d_ws, size_t ws_size,
                              hipStream_t stream) {
    const float* h   = (const float*)d_in[0];
    const int*   adj = (const int*)d_in[1];
    const float* W   = (const float*)d_in[2];
    const float* a   = (const float*)d_in[3];
    float* out = (float*)d_out;

    short* WhHiT = (short*)d_ws;                          // 2.13 MB
    short* WhLoT = WhHiT + (size_t)BB * FF * NP;          // 2.13 MB
    float* f1 = (float*)(WhLoT + (size_t)BB * FF * NP);   // 32 KB
    float* f2 = f1 + (size_t)BB * NN;                     // 32 KB
    u32* adjp = (u32*)(f2 + (size_t)BB * NN);             // 512 KB (total ~4.83 MB, proven)

    k_wh<<<(BB * NN) / 16, 256, 0, stream>>>(h, W, a, adj, WhHiT, WhLoT, f1, f2, adjp);
    k_attn<<<512, 512, 0, stream>>>(WhHiT, WhLoT, adjp, f1, f2, out);
}